// Round 5
// baseline (620.877 us; speedup 1.0000x reference)
//
#include <hip/hip_runtime.h>

#define S_LEN 2048
#define NL 51
#define LS 53
#define ST 51
#define EN 52
#define NBATCH 256
#define L2E 1.4426950408889634f
#define LN2 0.6931471805599453f

typedef float f32x4 __attribute__((ext_vector_type(4)));

__device__ __forceinline__ float rlane(float v, int l) {
    return __builtin_bit_cast(float, __builtin_amdgcn_readlane(__builtin_bit_cast(int, v), l));
}

// One block per batch element, 2 waves.
// Wave 0: forward recursion, multiplicative domain, lagged divisor (math
// identical to R2/R3/R4, all of which passed):
//   e_{t+1} = s_t * q_t,  s_t = E e_t,  q_t = gexp_t * rcp(ssum_{t-1}),
//   ssum = s[START] (row START of E is all-ones); applied divisors' log2 -> off2.
// R5: HYBRID matvec. k=0..27 broadcast via v_readlane (VALU pipe, issue-bound),
// k=28..55 via 7 ds_read_b128 broadcasts (DS pipe, latency hidden under the
// VALU half). E rows in 14 named f32x4 VGPRs. Logit feed: ONE global load per
// step into an 8-slot rotating register buffer (8-step = ~1700 cyc cover,
// single fine-grained vmcnt stream — no ganged waits).
// Wave 1: gold score (latency-tolerant global gathers), no LDS interaction.
__global__ __launch_bounds__(128, 1) void crf_kernel(
    const float* __restrict__ logits,   // [256, 2048, 51]
    const int*   __restrict__ labels,   // [256, 2048]
    const int*   __restrict__ lens,     // [256]
    const float* __restrict__ Tr,       // [53, 53]  (to, from)
    float*       __restrict__ out)      // [256]
{
    const int b   = blockIdx.x;
    const int tid = threadIdx.x;
    const int len = lens[b];
    __shared__ float sh_gold;
    __shared__ float sh_norm;
    __shared__ __align__(16) float sh_e[64];

    if (tid >= 64) {
        // ---- wave 1: gold score ----
        const int lid = tid - 64;
        const int* lb = labels + (long)b * S_LEN;
        const float* lg = logits + (long)b * S_LEN * NL;
        float p = 0.f;
        for (int t = lid; t < len; t += 64) {
            const int lab  = lb[t];
            const int prev = (t == 0) ? ST : lb[t - 1];
            p += lg[(long)t * NL + lab] + Tr[lab * LS + prev];
        }
        if (lid == 0) p += Tr[EN * LS + lb[len - 1]];   // final transition to END
#pragma unroll
        for (int off = 32; off > 0; off >>= 1)
            p += __shfl_down(p, off, 64);
        if (lid == 0) sh_gold = p;
    } else {
        // ---- wave 0: forward scan ----
        const int j  = tid;
        const int jj = (j < NL) ? j : 0;     // safe column for inactive lanes
        const float* trow = Tr + j * LS;

        f32x4 er0, er1, er2, er3, er4, er5, er6, er7, er8, er9, er10, er11, er12, er13;
#define GT(K)    (((j < LS) && ((K) < LS)) ? trow[(K)] : -1e30f)
#define LD4(V,B) { V.x = GT(B); V.y = GT((B)+1); V.z = GT((B)+2); V.w = GT((B)+3); }
        LD4(er0, 0)  LD4(er1, 4)  LD4(er2, 8)   LD4(er3, 12)
        LD4(er4, 16) LD4(er5, 20) LD4(er6, 24)  LD4(er7, 28)
        LD4(er8, 32) LD4(er9, 36) LD4(er10, 40) LD4(er11, 44)
        LD4(er12, 48) LD4(er13, 52)
#undef GT
#undef LD4
        float tmax = -1e30f;
#define MX4(V) tmax = fmaxf(tmax, fmaxf(fmaxf(V.x, V.y), fmaxf(V.z, V.w)));
        MX4(er0) MX4(er1) MX4(er2) MX4(er3) MX4(er4) MX4(er5) MX4(er6)
        MX4(er7) MX4(er8) MX4(er9) MX4(er10) MX4(er11) MX4(er12) MX4(er13)
#undef MX4
        // er = exp(T - tmax). Lanes j>=53: tmax=-1e30 -> er=1, but q stays 0
        // so their e stays 0 and sh_e[53..55]==0 kills those columns exactly.
#define EX4(V) { V.x = __builtin_amdgcn_exp2f((V.x - tmax) * L2E); \
                 V.y = __builtin_amdgcn_exp2f((V.y - tmax) * L2E); \
                 V.z = __builtin_amdgcn_exp2f((V.z - tmax) * L2E); \
                 V.w = __builtin_amdgcn_exp2f((V.w - tmax) * L2E); }
        EX4(er0) EX4(er1) EX4(er2) EX4(er3) EX4(er4) EX4(er5) EX4(er6)
        EX4(er7) EX4(er8) EX4(er9) EX4(er10) EX4(er11) EX4(er12) EX4(er13)
#undef EX4

        const float* lg = logits + (long)b * S_LEN * NL;

        float buf[8];
#pragma unroll
        for (int i = 0; i < 8; ++i)
            buf[i] = lg[i * NL + jj];          // rows 0..7 always in-bounds

        float e     = (j == ST) ? 1.f : 0.f;   // exp(alpha0)
        float off2  = 0.f;                     // sum of log2 of APPLIED divisors
        float lprev = 0.f;                     // log2 of divisor inside current q
        float nl0   = (j < NL) ? buf[0] : -100.f;
        float q     = __builtin_amdgcn_exp2f((nl0 + tmax) * L2E);   // gexp_0

        // hybrid matvec: k=0..27 readlane (VALU), k=28..55 LDS b128 broadcast
#define MATVEC(SOUT) { \
            sh_e[j] = e; \
            const f32x4* sp = (const f32x4*)sh_e; \
            f32x4 l7 = sp[7], l8 = sp[8], l9 = sp[9], l10 = sp[10]; \
            f32x4 l11 = sp[11], l12 = sp[12], l13 = sp[13]; \
            float v0 = 0.f, v1 = 0.f, v2 = 0.f, v3 = 0.f; \
            v0 = fmaf(rlane(e, 0),  er0.x, v0); v1 = fmaf(rlane(e, 1),  er0.y, v1); \
            v2 = fmaf(rlane(e, 2),  er0.z, v2); v3 = fmaf(rlane(e, 3),  er0.w, v3); \
            v0 = fmaf(rlane(e, 4),  er1.x, v0); v1 = fmaf(rlane(e, 5),  er1.y, v1); \
            v2 = fmaf(rlane(e, 6),  er1.z, v2); v3 = fmaf(rlane(e, 7),  er1.w, v3); \
            v0 = fmaf(rlane(e, 8),  er2.x, v0); v1 = fmaf(rlane(e, 9),  er2.y, v1); \
            v2 = fmaf(rlane(e, 10), er2.z, v2); v3 = fmaf(rlane(e, 11), er2.w, v3); \
            v0 = fmaf(rlane(e, 12), er3.x, v0); v1 = fmaf(rlane(e, 13), er3.y, v1); \
            v2 = fmaf(rlane(e, 14), er3.z, v2); v3 = fmaf(rlane(e, 15), er3.w, v3); \
            v0 = fmaf(rlane(e, 16), er4.x, v0); v1 = fmaf(rlane(e, 17), er4.y, v1); \
            v2 = fmaf(rlane(e, 18), er4.z, v2); v3 = fmaf(rlane(e, 19), er4.w, v3); \
            v0 = fmaf(rlane(e, 20), er5.x, v0); v1 = fmaf(rlane(e, 21), er5.y, v1); \
            v2 = fmaf(rlane(e, 22), er5.z, v2); v3 = fmaf(rlane(e, 23), er5.w, v3); \
            v0 = fmaf(rlane(e, 24), er6.x, v0); v1 = fmaf(rlane(e, 25), er6.y, v1); \
            v2 = fmaf(rlane(e, 26), er6.z, v2); v3 = fmaf(rlane(e, 27), er6.w, v3); \
            f32x4 a0 = l7 * er7,  a1 = l8 * er8,  a2 = l9 * er9,  a3 = l10 * er10; \
            a0 += l11 * er11; a1 += l12 * er12; a2 += l13 * er13; \
            f32x4 aa = (a0 + a1) + (a2 + a3); \
            SOUT = ((v0 + v1) + (v2 + v3)) + ((aa.x + aa.y) + (aa.z + aa.w)); }

#define STEP(NLRAW) { \
            float nl = (j < NL) ? (NLRAW) : -100.f; \
            float s; MATVEC(s); \
            e = s * q; \
            float ssum = rlane(s, ST); \
            off2 += lprev; \
            lprev = __builtin_amdgcn_logf(ssum); \
            q = __builtin_amdgcn_exp2f((nl + tmax) * L2E) * __builtin_amdgcn_rcpf(ssum); }

        int t = 0;
#pragma unroll 1
        while (t + 8 <= len) {
#pragma unroll
            for (int i = 0; i < 8; ++i) {
                float nlraw = buf[(i + 1) & 7];       // logit[t+i+1]
                int ti = t + i + 8;                   // prefetch 8 ahead
                ti = (ti < S_LEN) ? ti : (S_LEN - 1); // clamp: in-bounds, unused if >= len
                float pf = lg[(long)ti * NL + jj];
                STEP(nlraw)
                buf[i] = pf;                          // slot i now holds logit[t+i+8]
            }
            t += 8;
        }
        // tail (< 8 steps); slot m holds logit[t+m]; last step's "next" logit
        // (row len <= 2047) is in-bounds and its q is never applied.
#pragma unroll
        for (int i = 0; i < 8; ++i) {
            if (t + i < len) {
                float nlraw = buf[(i + 1) & 7];
                STEP(nlraw)
            }
        }

        // norm = logsumexp_j(alpha[j] + T[END, j]) : one more matvec, row END
        float s; MATVEC(s);
        float sEnd  = rlane(s, EN);
        float tmEnd = rlane(tmax, EN);
        if (j == 0)
            sh_norm = (off2 + __builtin_amdgcn_logf(sEnd)) * LN2 + tmEnd;
#undef STEP
#undef MATVEC
    }
    __syncthreads();
    if (tid == 0) out[b] = sh_gold - sh_norm;
}

extern "C" void kernel_launch(void* const* d_in, const int* in_sizes, int n_in,
                              void* d_out, int out_size, void* d_ws, size_t ws_size,
                              hipStream_t stream) {
    const float* logits = (const float*)d_in[0];
    const int*   labels = (const int*)d_in[1];
    const int*   lens   = (const int*)d_in[2];
    const float* Tr     = (const float*)d_in[3];
    float*       out    = (float*)d_out;
    crf_kernel<<<NBATCH, 128, 0, stream>>>(logits, labels, lens, Tr, out);
}

// Round 6
// 526.479 us; speedup vs baseline: 1.1793x; 1.1793x over previous
//
#include <hip/hip_runtime.h>

#define S_LEN 2048
#define NL 51
#define LS 53
#define ST 51
#define EN 52
#define NBATCH 256
#define L2E 1.4426950408889634f
#define LN2 0.6931471805599453f

typedef float f32x4 __attribute__((ext_vector_type(4)));

__device__ __forceinline__ float rlane(float v, int l) {
    return __builtin_bit_cast(float, __builtin_amdgcn_readlane(__builtin_bit_cast(int, v), l));
}

// One block per batch element, 2 waves.
// Wave 0: forward recursion, multiplicative domain, lagged divisor (math
// identical to R2..R5, all passed):
//   e_{t+1} = s_t * q_t,  s_t = E e_t,  q_t = gexp_t * rcp(ssum_{t-1}),
//   ssum = s[START] (row START of E is all-ones); applied divisors' log2 -> off2.
// R6: BATCHED readlane matvec — all 53 broadcasts issue first (SGPR dests),
// sched_barrier(0), then all 54 FMAs. This removes the per-pair
// VALU-writes-SGPR -> VALU-reads-SGPR hazard suspected of costing ~7 cyc x53.
// No LDS in the scan wave at all. Prefetch depth 4, literal-indexed slots.
// Wave 1: gold score (latency-tolerant global gathers).
__global__ __launch_bounds__(128, 1) void crf_kernel(
    const float* __restrict__ logits,   // [256, 2048, 51]
    const int*   __restrict__ labels,   // [256, 2048]
    const int*   __restrict__ lens,     // [256]
    const float* __restrict__ Tr,       // [53, 53]  (to, from)
    float*       __restrict__ out)      // [256]
{
    const int b   = blockIdx.x;
    const int tid = threadIdx.x;
    const int len = lens[b];
    __shared__ float sh_gold;
    __shared__ float sh_norm;

    if (tid >= 64) {
        // ---- wave 1: gold score ----
        const int lid = tid - 64;
        const int* lb = labels + (long)b * S_LEN;
        const float* lg = logits + (long)b * S_LEN * NL;
        float p = 0.f;
        for (int t = lid; t < len; t += 64) {
            const int lab  = lb[t];
            const int prev = (t == 0) ? ST : lb[t - 1];
            p += lg[(long)t * NL + lab] + Tr[lab * LS + prev];
        }
        if (lid == 0) p += Tr[EN * LS + lb[len - 1]];   // final transition to END
#pragma unroll
        for (int off = 32; off > 0; off >>= 1)
            p += __shfl_down(p, off, 64);
        if (lid == 0) sh_gold = p;
    } else {
        // ---- wave 0: forward scan ----
        const int j  = tid;
        const int jj = (j < NL) ? j : 0;     // safe column for inactive lanes
        const float* trow = Tr + j * LS;

        f32x4 er0, er1, er2, er3, er4, er5, er6, er7, er8, er9, er10, er11, er12, er13;
#define GT(K)    (((j < LS) && ((K) < LS)) ? trow[(K)] : -1e30f)
#define LD4(V,B) { V.x = GT(B); V.y = GT((B)+1); V.z = GT((B)+2); V.w = GT((B)+3); }
        LD4(er0, 0)  LD4(er1, 4)  LD4(er2, 8)   LD4(er3, 12)
        LD4(er4, 16) LD4(er5, 20) LD4(er6, 24)  LD4(er7, 28)
        LD4(er8, 32) LD4(er9, 36) LD4(er10, 40) LD4(er11, 44)
        LD4(er12, 48) LD4(er13, 52)
#undef GT
#undef LD4
        float tmax = -1e30f;
#define MX4(V) tmax = fmaxf(tmax, fmaxf(fmaxf(V.x, V.y), fmaxf(V.z, V.w)));
        MX4(er0) MX4(er1) MX4(er2) MX4(er3) MX4(er4) MX4(er5) MX4(er6)
        MX4(er7) MX4(er8) MX4(er9) MX4(er10) MX4(er11) MX4(er12) MX4(er13)
#undef MX4
        // er = exp(T - tmax). Lanes j>=53: tmax=-1e30 -> er=1, but their q
        // stays 0 (nl=-100, tmax=-1e30) so e stays 0 and they contribute 0.
#define EX4(V) { V.x = __builtin_amdgcn_exp2f((V.x - tmax) * L2E); \
                 V.y = __builtin_amdgcn_exp2f((V.y - tmax) * L2E); \
                 V.z = __builtin_amdgcn_exp2f((V.z - tmax) * L2E); \
                 V.w = __builtin_amdgcn_exp2f((V.w - tmax) * L2E); }
        EX4(er0) EX4(er1) EX4(er2) EX4(er3) EX4(er4) EX4(er5) EX4(er6)
        EX4(er7) EX4(er8) EX4(er9) EX4(er10) EX4(er11) EX4(er12) EX4(er13)
#undef EX4

        const float* lg = logits + (long)b * S_LEN * NL;

        float buf[4];
        buf[0] = lg[0 * NL + jj];
        buf[1] = lg[1 * NL + jj];
        buf[2] = lg[2 * NL + jj];
        buf[3] = lg[3 * NL + jj];          // rows 0..3 always in-bounds (len>=1)

        float e     = (j == ST) ? 1.f : 0.f;   // exp(alpha0)
        float off2  = 0.f;                     // sum of log2 of APPLIED divisors
        float lprev = 0.f;                     // log2 of divisor inside current q
        float nl0   = (j < NL) ? buf[0] : -100.f;
        float q     = __builtin_amdgcn_exp2f((nl0 + tmax) * L2E);   // gexp_0

        // phase-split matvec: 53 readlanes (SGPRs), barrier, 54 fmas
#define RL4(G) float b##G##0 = rlane(e, 4*G), b##G##1 = rlane(e, 4*G+1), \
                     b##G##2 = rlane(e, 4*G+2), b##G##3 = rlane(e, 4*G+3);
#define FM4(G, EV) { ax = fmaf(b##G##0, EV.x, ax); ay = fmaf(b##G##1, EV.y, ay); \
                     az = fmaf(b##G##2, EV.z, az); aw = fmaf(b##G##3, EV.w, aw); }
#define MATVEC(SOUT) { \
            RL4(0) RL4(1) RL4(2) RL4(3) RL4(4) RL4(5) RL4(6) \
            RL4(7) RL4(8) RL4(9) RL4(10) RL4(11) RL4(12) \
            float b130 = rlane(e, 52); \
            __builtin_amdgcn_sched_barrier(0); \
            float ax = 0.f, ay = 0.f, az = 0.f, aw = 0.f; \
            FM4(0, er0) FM4(1, er1) FM4(2, er2) FM4(3, er3) FM4(4, er4) \
            FM4(5, er5) FM4(6, er6) FM4(7, er7) FM4(8, er8) FM4(9, er9) \
            FM4(10, er10) FM4(11, er11) FM4(12, er12) \
            ax = fmaf(b130, er13.x, ax); \
            SOUT = (ax + ay) + (az + aw); }

#define STEP(NLRAW) { \
            float nl = (j < NL) ? (NLRAW) : -100.f; \
            float s; MATVEC(s); \
            e = s * q; \
            float ssum = rlane(s, ST); \
            off2 += lprev; \
            lprev = __builtin_amdgcn_logf(ssum); \
            q = __builtin_amdgcn_exp2f((nl + tmax) * L2E) * __builtin_amdgcn_rcpf(ssum); }

        int t = 0;
#pragma unroll 1
        while (t + 4 <= len) {
            {   // i = 0  (t+4 <= len <= 2047: in-bounds, no clamp)
                float pf = lg[(long)(t + 4) * NL + jj];
                STEP(buf[1])
                buf[0] = pf;
            }
            {   // i = 1
                int ti = t + 5; ti = (ti < S_LEN) ? ti : (S_LEN - 1);
                float pf = lg[(long)ti * NL + jj];
                STEP(buf[2])
                buf[1] = pf;
            }
            {   // i = 2
                int ti = t + 6; ti = (ti < S_LEN) ? ti : (S_LEN - 1);
                float pf = lg[(long)ti * NL + jj];
                STEP(buf[3])
                buf[2] = pf;
            }
            {   // i = 3
                int ti = t + 7; ti = (ti < S_LEN) ? ti : (S_LEN - 1);
                float pf = lg[(long)ti * NL + jj];
                STEP(buf[0])
                buf[3] = pf;
            }
            t += 4;
        }
        // tail: <= 3 steps; slot m holds row t+m; "next" logit of the last
        // step is in-bounds (row <= len <= 2047) and its q is never applied.
#pragma unroll
        for (int i = 0; i < 4; ++i) {
            if (t + i < len) {
                STEP(buf[(i + 1) & 3])
            }
        }

        // norm = logsumexp_j(alpha[j] + T[END, j]) : one more matvec, row END
        float s; MATVEC(s);
        float sEnd  = rlane(s, EN);
        float tmEnd = rlane(tmax, EN);
        if (j == 0)
            sh_norm = (off2 + __builtin_amdgcn_logf(sEnd)) * LN2 + tmEnd;
#undef STEP
#undef MATVEC
#undef RL4
#undef FM4
    }
    __syncthreads();
    if (tid == 0) out[b] = sh_gold - sh_norm;
}

extern "C" void kernel_launch(void* const* d_in, const int* in_sizes, int n_in,
                              void* d_out, int out_size, void* d_ws, size_t ws_size,
                              hipStream_t stream) {
    const float* logits = (const float*)d_in[0];
    const int*   labels = (const int*)d_in[1];
    const int*   lens   = (const int*)d_in[2];
    const float* Tr     = (const float*)d_in[3];
    float*       out    = (float*)d_out;
    crf_kernel<<<NBATCH, 128, 0, stream>>>(logits, labels, lens, Tr, out);
}